// Round 7
// baseline (284.305 us; speedup 1.0000x reference)
//
#include <hip/hip_runtime.h>
#include <hip/hip_bf16.h>
#include <math.h>

#define DD 64
#define CAP 64
#define LN_EPS 1e-5f

__device__ __forceinline__ float bfl(unsigned u) {            // low bf16 of dword
    return __uint_as_float(u << 16);
}
__device__ __forceinline__ float bfh(unsigned u) {            // high bf16 of dword
    return __uint_as_float(u & 0xffff0000u);
}

// ---------------- Kernel A: projections -> bf16. 64 nodes/block, 4 waves:
// waves 0,1: qk nodes [0,32)/[32,64); waves 2,3: v same split.
// x staged TRANSPOSED in LDS (lx[dim][node], stride 66 -> 8B-aligned float2,
// broadcast reads = conflict-free, DS pipe overlaps VALU). Weights in VGPRs.
__global__ __launch_bounds__(256) void proj_kernel(
    const float* __restrict__ x,
    const float* __restrict__ qk_w, const float* __restrict__ qk_b,
    const float* __restrict__ v_w,  const float* __restrict__ v_b,
    __hip_bfloat16* __restrict__ qk, __hip_bfloat16* __restrict__ v, int n)
{
    __shared__ float lx[64 * 66];                 // 16.9 KB
    int tid = threadIdx.x;
    int base = blockIdx.x * 64;
    for (int i = tid; i < 64 * 64; i += 256) {
        int nl = i >> 6, dim = i & 63;
        int node = base + nl;
        float val = (node < n) ? x[(size_t)node * 64 + dim] : 0.f;
        lx[dim * 66 + nl] = val;                  // 4-way write conflict, one-time
    }

    int wave = tid >> 6, lane = tid & 63;
    const float* W = (wave & 2) ? v_w : qk_w;
    const float* B = (wave & 2) ? v_b : qk_b;
    __hip_bfloat16* O = (wave & 2) ? v : qk;
    float w[64];
    #pragma unroll
    for (int j = 0; j < 64; ++j) w[j] = W[lane * 64 + j];
    float bias = B[lane];
    __syncthreads();

    int nb = base + (wave & 1) * 32;
    for (int k = 0; k < 32; k += 2) {
        int n0 = nb + k;
        if (n0 >= n) break;                       // uniform per wave
        int loc = (wave & 1) * 32 + k;
        float a0 = bias, a1 = bias;
        #pragma unroll
        for (int j = 0; j < 64; ++j) {
            float2 xj = *(const float2*)&lx[j * 66 + loc];   // ds_read_b64 bcast
            a0 = fmaf(xj.x, w[j], a0);
            a1 = fmaf(xj.y, w[j], a1);
        }
        O[(size_t)n0 * 64 + lane] = __float2bfloat16(a0);
        if (n0 + 1 < n) O[(size_t)(n0 + 1) * 64 + lane] = __float2bfloat16(a1);
    }
}

// ---------------- Kernel B: fused bucket build — 1 edge/thread for max TLP
// (atomic RMW latency hides behind wave count, not per-thread batching).
__global__ __launch_bounds__(256) void build_kernel(
    const int* __restrict__ eidx, int* __restrict__ deg, int* __restrict__ bucket, int E)
{
    int i = blockIdx.x * 256 + threadIdx.x;
    if (i < E) {
        int s = eidx[i];
        int d = eidx[E + i];
        int r = atomicAdd(&deg[d], 1);
        if (r < CAP) bucket[(d << 6) + r] = s;    // 256B row = 4 cachelines
    }
}

// ---------------- Kernel E: per-node attention + o-proj + residual + LayerNorm
// 4 waves/block = 4 nodes. Wave = 8x8-lane subgroups; 2-deep unroll -> 16
// edges in flight (32 outstanding 16B gathers). Fixed softmax shift m=5.
__global__ __launch_bounds__(256) void attn_kernel(
    const float* __restrict__ x,
    const __hip_bfloat16* __restrict__ qk, const __hip_bfloat16* __restrict__ v,
    const int* __restrict__ deg, const int* __restrict__ bucket,
    const float* __restrict__ o_w, const float* __restrict__ o_b,
    const float* __restrict__ ln_g, const float* __restrict__ ln_b,
    float* __restrict__ out, int n)
{
    __shared__ float low[64 * 68];                 // o_w, stride 68 (16B-aligned)
    __shared__ float outd_lds[4][64];
    int tid = threadIdx.x;
    int wave = tid >> 6, lane = tid & 63;
    int node = blockIdx.x * 4 + wave;
    int sub = lane >> 3;                           // edge slot 0..7
    int sl  = lane & 7;                            // dim octant

    // issue per-node global loads BEFORE staging to overlap latency
    uint4 qu = {0,0,0,0};
    float xres = 0.f;
    int dn = 0;
    if (node < n) {
        qu   = ((const uint4*)(qk + ((size_t)node << 6)))[sl];
        xres = x[((size_t)node << 6) + lane];
        dn   = deg[node];
        if (dn > CAP) dn = CAP;
    }

    for (int i = tid; i < 64 * 64; i += 256)
        low[(i >> 6) * 68 + (i & 63)] = o_w[i];
    __syncthreads();
    if (node >= n) return;

    float qf0 = bfl(qu.x), qf1 = bfh(qu.x), qf2 = bfl(qu.y), qf3 = bfh(qu.y);
    float qf4 = bfl(qu.z), qf5 = bfh(qu.z), qf6 = bfl(qu.w), qf7 = bfh(qu.w);
    const int* bkt = bucket + ((size_t)node << 6);

    float s = 0.f;
    float a0 = 0.f, a1 = 0.f, a2 = 0.f, a3 = 0.f;
    float a4 = 0.f, a5 = 0.f, a6 = 0.f, a7 = 0.f;

    for (int base = 0; base < dn; base += 16) {    // 16 edges/iter, masked
        int idx0 = base + sub;
        int idx1 = idx0 + 8;
        bool v0 = idx0 < dn, v1 = idx1 < dn;
        int s0 = bkt[v0 ? idx0 : 0];
        int s1 = bkt[v1 ? idx1 : 0];
        uint4 k0 = ((const uint4*)(qk + ((size_t)s0 << 6)))[sl];
        uint4 k1 = ((const uint4*)(qk + ((size_t)s1 << 6)))[sl];
        uint4 u0 = ((const uint4*)(v  + ((size_t)s0 << 6)))[sl];
        uint4 u1 = ((const uint4*)(v  + ((size_t)s1 << 6)))[sl];
        float p0 = qf0 * bfl(k0.x) + qf1 * bfh(k0.x)
                 + qf2 * bfl(k0.y) + qf3 * bfh(k0.y)
                 + qf4 * bfl(k0.z) + qf5 * bfh(k0.z)
                 + qf6 * bfl(k0.w) + qf7 * bfh(k0.w);
        float p1 = qf0 * bfl(k1.x) + qf1 * bfh(k1.x)
                 + qf2 * bfl(k1.y) + qf3 * bfh(k1.y)
                 + qf4 * bfl(k1.z) + qf5 * bfh(k1.z)
                 + qf6 * bfl(k1.w) + qf7 * bfh(k1.w);
        p0 += __shfl_xor(p0, 1); p1 += __shfl_xor(p1, 1);
        p0 += __shfl_xor(p0, 2); p1 += __shfl_xor(p1, 2);
        p0 += __shfl_xor(p0, 4); p1 += __shfl_xor(p1, 4);
        float sc0 = fminf(5.f, fmaxf(-5.f, p0 * 0.125f));
        float sc1 = fminf(5.f, fmaxf(-5.f, p1 * 0.125f));
        float pe0 = v0 ? __expf(sc0 - 5.f) : 0.f;
        float pe1 = v1 ? __expf(sc1 - 5.f) : 0.f;
        s += pe0 + pe1;
        a0 += pe0 * bfl(u0.x) + pe1 * bfl(u1.x);
        a1 += pe0 * bfh(u0.x) + pe1 * bfh(u1.x);
        a2 += pe0 * bfl(u0.y) + pe1 * bfl(u1.y);
        a3 += pe0 * bfh(u0.y) + pe1 * bfh(u1.y);
        a4 += pe0 * bfl(u0.z) + pe1 * bfl(u1.z);
        a5 += pe0 * bfh(u0.z) + pe1 * bfh(u1.z);
        a6 += pe0 * bfl(u0.w) + pe1 * bfl(u1.w);
        a7 += pe0 * bfh(u0.w) + pe1 * bfh(u1.w);
    }

    // merge the 8 subgroup partials (plain sums — fixed shift): xor 8,16,32
    #pragma unroll
    for (int w = 8; w <= 32; w <<= 1) {
        s  += __shfl_xor(s,  w);
        a0 += __shfl_xor(a0, w); a1 += __shfl_xor(a1, w);
        a2 += __shfl_xor(a2, w); a3 += __shfl_xor(a3, w);
        a4 += __shfl_xor(a4, w); a5 += __shfl_xor(a5, w);
        a6 += __shfl_xor(a6, w); a7 += __shfl_xor(a7, w);
    }

    float inv = (dn > 0) ? (1.0f / s) : 0.f;       // s>0 iff deg>0 (pe >= e^-10)
    if (sub == 0) {                                 // lanes 0..7 write outd
        float4 lo = make_float4(a0 * inv, a1 * inv, a2 * inv, a3 * inv);
        float4 hi = make_float4(a4 * inv, a5 * inv, a6 * inv, a7 * inv);
        *(float4*)&outd_lds[wave][sl * 8]     = lo;
        *(float4*)&outd_lds[wave][sl * 8 + 4] = hi;
    }
    // wave-local LDS dependence: compiler inserts lgkmcnt wait

    // o-projection: y[lane] = sum_j outd[j] * o_w[lane][j] + o_b[lane]
    float y = o_b[lane];
    const float4* lw = (const float4*)(low + lane * 68);
    const float4* od = (const float4*)&outd_lds[wave][0];
    #pragma unroll
    for (int i = 0; i < 16; ++i) {
        float4 wv = lw[i];                         // ds_read_b128 (conflict-free)
        float4 ov = od[i];                         // broadcast ds_read_b128
        y = fmaf(ov.x, wv.x, y);
        y = fmaf(ov.y, wv.y, y);
        y = fmaf(ov.z, wv.z, y);
        y = fmaf(ov.w, wv.w, y);
    }

    float h = y + xres;
    float mean = h;
    #pragma unroll
    for (int w = 1; w <= 32; w <<= 1) mean += __shfl_xor(mean, w);
    mean *= (1.f / 64.f);
    float d0 = h - mean;
    float dv = d0 * d0;
    #pragma unroll
    for (int w = 1; w <= 32; w <<= 1) dv += __shfl_xor(dv, w);
    dv *= (1.f / 64.f);
    float r = rsqrtf(dv + LN_EPS);
    out[((size_t)node << 6) + lane] = d0 * r * ln_g[lane] + ln_b[lane];
}

extern "C" void kernel_launch(void* const* d_in, const int* in_sizes, int n_in,
                              void* d_out, int out_size, void* d_ws, size_t ws_size,
                              hipStream_t stream)
{
    const float* x    = (const float*)d_in[0];
    const int*   eidx = (const int*)  d_in[1];
    const float* qk_w = (const float*)d_in[2];
    const float* qk_b = (const float*)d_in[3];
    const float* v_w  = (const float*)d_in[4];
    const float* v_b  = (const float*)d_in[5];
    const float* o_w  = (const float*)d_in[6];
    const float* o_b  = (const float*)d_in[7];
    const float* ln_g = (const float*)d_in[8];
    const float* ln_b = (const float*)d_in[9];

    const int n = in_sizes[0] / DD;      // 100000
    const int E = in_sizes[1] / 2;       // 1280000

    char* ws = (char*)d_ws;
    size_t off = 0;
    __hip_bfloat16* qk = (__hip_bfloat16*)(ws + off); off += (size_t)n * DD * 2;  // 12.8 MB
    __hip_bfloat16* v  = (__hip_bfloat16*)(ws + off); off += (size_t)n * DD * 2;  // 12.8 MB
    int* deg    = (int*)(ws + off); off += (size_t)n * 4;                         // 0.4 MB
    int* bucket = (int*)(ws + off); off += (size_t)n * CAP * 4;                   // 25.6 MB

    hipMemsetAsync(deg, 0, (size_t)n * 4, stream);

    proj_kernel<<<(n + 63) / 64, 256, 0, stream>>>(x, qk_w, qk_b, v_w, v_b, qk, v, n);
    build_kernel<<<(E + 255) / 256, 256, 0, stream>>>(eidx, deg, bucket, E);
    attn_kernel<<<(n + 3) / 4, 256, 0, stream>>>(x, qk, v, deg, bucket,
                                                 o_w, o_b, ln_g, ln_b,
                                                 (float*)d_out, n);
}

// Round 8
// 230.823 us; speedup vs baseline: 1.2317x; 1.2317x over previous
//
#include <hip/hip_runtime.h>
#include <hip/hip_bf16.h>
#include <math.h>

#define DD 64
#define CAP 64
#define LN_EPS 1e-5f

__device__ __forceinline__ float bf2f(unsigned short u) {
    return __uint_as_float(((unsigned)u) << 16);
}
__device__ __forceinline__ float rlane(float v, int l) {
    return __int_as_float(__builtin_amdgcn_readlane(__float_as_int(v), l));
}

// ---------------- Kernel 1 (fused): blocks [0,PB) = projections -> interleaved
// bf16 QKV rows (256B/node: qk[0..63] then v[0..63]); blocks [PB,..) = bucket
// build (1 edge/thread for max TLP on the atomics).
// Proj: weights in 64 VGPRs/lane (lane = out col), x broadcast via v_readlane.
__global__ __launch_bounds__(256) void prep_kernel(
    const float* __restrict__ x,
    const float* __restrict__ qk_w, const float* __restrict__ qk_b,
    const float* __restrict__ v_w,  const float* __restrict__ v_b,
    const int* __restrict__ eidx, int* __restrict__ deg,
    __hip_bfloat16* __restrict__ qkv, int* __restrict__ bucket,
    int n, int E, int PB)
{
    int bid = blockIdx.x;
    if (bid < PB) {
        int tid = threadIdx.x;
        int wave = tid >> 6, lane = tid & 63;
        const float* W = (wave & 2) ? v_w : qk_w;
        const float* B = (wave & 2) ? v_b : qk_b;
        int half = (wave & 2) ? 64 : 0;
        float w[64];
        #pragma unroll
        for (int j = 0; j < 64; ++j) w[j] = W[lane * 64 + j];
        float bias = B[lane];
        int base = bid * 64 + (wave & 1) * 32;
        for (int k = 0; k < 32; k += 2) {
            int n0 = base + k, n1 = n0 + 1;
            if (n0 >= n) break;                      // uniform per wave
            float xv0 = x[(size_t)n0 * 64 + lane];
            float xv1 = (n1 < n) ? x[(size_t)n1 * 64 + lane] : 0.f;
            float a0 = bias, a1 = bias;
            #pragma unroll
            for (int j = 0; j < 64; ++j) {
                a0 = fmaf(rlane(xv0, j), w[j], a0);
                a1 = fmaf(rlane(xv1, j), w[j], a1);
            }
            qkv[(size_t)n0 * 128 + half + lane] = __float2bfloat16(a0);
            if (n1 < n) qkv[(size_t)n1 * 128 + half + lane] = __float2bfloat16(a1);
        }
    } else {
        int i = (bid - PB) * 256 + threadIdx.x;
        if (i < E) {
            int s = eidx[i];
            int d = eidx[E + i];
            int r = atomicAdd(&deg[d], 1);
            if (r < CAP) bucket[(d << 6) + r] = s;   // 256B row
        }
    }
}

// ---------------- Kernel 2: per-node attention + o-proj + residual + LayerNorm
// 4 waves/block = 4 nodes. Wave = 4x16-lane subgroups (lane holds 4 dims,
// bf16x4 = 8B), 2-deep unroll -> 8 edges in flight, clean main loop + tail.
// Interleaved QKV: one 32-bit byte offset per edge, v half at +128 immediate.
// Fixed softmax shift m=5 (scores clamped to [-5,5]).
__global__ __launch_bounds__(256) void attn_kernel(
    const float* __restrict__ x, const __hip_bfloat16* __restrict__ qkv,
    const int* __restrict__ deg, const int* __restrict__ bucket,
    const float* __restrict__ o_w, const float* __restrict__ o_b,
    const float* __restrict__ ln_g, const float* __restrict__ ln_b,
    float* __restrict__ out, int n)
{
    __shared__ float low[64 * 68];                 // o_w, stride 68 (16B-aligned)
    int tid = threadIdx.x;
    for (int i = tid; i < 64 * 64; i += 256)
        low[(i >> 6) * 68 + (i & 63)] = o_w[i];
    __syncthreads();

    int wave = tid >> 6, lane = tid & 63;
    int node = blockIdx.x * 4 + wave;
    if (node >= n) return;

    int sub = lane >> 4;                           // edge slot 0..3
    int sl  = lane & 15;                           // dims sl*4 .. sl*4+3

    const char* base = (const char*)qkv;
    ushort4 qu = *(const ushort4*)(base + (size_t)node * 256 + sl * 8);
    float4 q4 = make_float4(bf2f(qu.x), bf2f(qu.y), bf2f(qu.z), bf2f(qu.w));
    int dn = deg[node]; if (dn > CAP) dn = CAP;
    const int* bkt = bucket + (node << 6);

    float s = 0.f;
    float4 acc = {0.f, 0.f, 0.f, 0.f};

    int idx = sub;
    for (; idx + 4 < dn; idx += 8) {               // 2 edges/subgroup iter
        int s0 = bkt[idx];
        int s1 = bkt[idx + 4];
        unsigned o0 = ((unsigned)s0 << 8) + (sl << 3);
        unsigned o1 = ((unsigned)s1 << 8) + (sl << 3);
        ushort4 k0 = *(const ushort4*)(base + o0);
        ushort4 k1 = *(const ushort4*)(base + o1);
        ushort4 u0 = *(const ushort4*)(base + o0 + 128);
        ushort4 u1 = *(const ushort4*)(base + o1 + 128);
        float p0 = q4.x*bf2f(k0.x) + q4.y*bf2f(k0.y) + q4.z*bf2f(k0.z) + q4.w*bf2f(k0.w);
        float p1 = q4.x*bf2f(k1.x) + q4.y*bf2f(k1.y) + q4.z*bf2f(k1.z) + q4.w*bf2f(k1.w);
        #pragma unroll
        for (int w = 1; w <= 8; w <<= 1) { p0 += __shfl_xor(p0, w); p1 += __shfl_xor(p1, w); }
        float sc0 = fminf(5.f, fmaxf(-5.f, p0 * 0.125f));
        float sc1 = fminf(5.f, fmaxf(-5.f, p1 * 0.125f));
        float pe0 = __expf(sc0 - 5.f);
        float pe1 = __expf(sc1 - 5.f);
        s += pe0 + pe1;
        acc.x += pe0 * bf2f(u0.x) + pe1 * bf2f(u1.x);
        acc.y += pe0 * bf2f(u0.y) + pe1 * bf2f(u1.y);
        acc.z += pe0 * bf2f(u0.z) + pe1 * bf2f(u1.z);
        acc.w += pe0 * bf2f(u0.w) + pe1 * bf2f(u1.w);
    }
    if (idx < dn) {
        int s0 = bkt[idx];
        unsigned o0 = ((unsigned)s0 << 8) + (sl << 3);
        ushort4 k0 = *(const ushort4*)(base + o0);
        ushort4 u0 = *(const ushort4*)(base + o0 + 128);
        float p0 = q4.x*bf2f(k0.x) + q4.y*bf2f(k0.y) + q4.z*bf2f(k0.z) + q4.w*bf2f(k0.w);
        #pragma unroll
        for (int w = 1; w <= 8; w <<= 1) p0 += __shfl_xor(p0, w);
        float sc0 = fminf(5.f, fmaxf(-5.f, p0 * 0.125f));
        float pe0 = __expf(sc0 - 5.f);
        s += pe0;
        acc.x += pe0 * bf2f(u0.x); acc.y += pe0 * bf2f(u0.y);
        acc.z += pe0 * bf2f(u0.z); acc.w += pe0 * bf2f(u0.w);
    }

    // merge 4 subgroup partials (plain sums, fixed shift) — butterfly:
    // afterwards every lane holds totals for its sl's 4 dims.
    s += __shfl_xor(s, 16); s += __shfl_xor(s, 32);
    acc.x += __shfl_xor(acc.x, 16); acc.x += __shfl_xor(acc.x, 32);
    acc.y += __shfl_xor(acc.y, 16); acc.y += __shfl_xor(acc.y, 32);
    acc.z += __shfl_xor(acc.z, 16); acc.z += __shfl_xor(acc.z, 32);
    acc.w += __shfl_xor(acc.w, 16); acc.w += __shfl_xor(acc.w, 32);

    float inv = (dn > 0) ? (1.0f / s) : 0.f;       // s>0 iff deg>0 (pe >= e^-10)
    acc.x *= inv; acc.y *= inv; acc.z *= inv; acc.w *= inv;

    // o-projection: outd[4i+c] lives in lane i comp c -> readlane broadcast;
    // weights via ds_read_b128 (stride-68, 16B-aligned, conflict-free).
    float y = o_b[lane];
    const float4* lw = (const float4*)(low + lane * 68);
    #pragma unroll
    for (int i = 0; i < 16; ++i) {
        float4 wv = lw[i];
        y = fmaf(rlane(acc.x, i), wv.x, y);
        y = fmaf(rlane(acc.y, i), wv.y, y);
        y = fmaf(rlane(acc.z, i), wv.z, y);
        y = fmaf(rlane(acc.w, i), wv.w, y);
    }

    float h = y + x[(size_t)node * 64 + lane];
    float mean = h;
    #pragma unroll
    for (int w = 1; w <= 32; w <<= 1) mean += __shfl_xor(mean, w);
    mean *= (1.f / 64.f);
    float d0 = h - mean;
    float dv = d0 * d0;
    #pragma unroll
    for (int w = 1; w <= 32; w <<= 1) dv += __shfl_xor(dv, w);
    dv *= (1.f / 64.f);
    float r = rsqrtf(dv + LN_EPS);
    out[(size_t)node * 64 + lane] = d0 * r * ln_g[lane] + ln_b[lane];
}

extern "C" void kernel_launch(void* const* d_in, const int* in_sizes, int n_in,
                              void* d_out, int out_size, void* d_ws, size_t ws_size,
                              hipStream_t stream)
{
    const float* x    = (const float*)d_in[0];
    const int*   eidx = (const int*)  d_in[1];
    const float* qk_w = (const float*)d_in[2];
    const float* qk_b = (const float*)d_in[3];
    const float* v_w  = (const float*)d_in[4];
    const float* v_b  = (const float*)d_in[5];
    const float* o_w  = (const float*)d_in[6];
    const float* o_b  = (const float*)d_in[7];
    const float* ln_g = (const float*)d_in[8];
    const float* ln_b = (const float*)d_in[9];

    const int n = in_sizes[0] / DD;      // 100000
    const int E = in_sizes[1] / 2;       // 1280000

    char* ws = (char*)d_ws;
    size_t off = 0;
    __hip_bfloat16* qkv = (__hip_bfloat16*)(ws + off); off += (size_t)n * 128 * 2; // 25.6 MB
    int* deg    = (int*)(ws + off); off += (size_t)n * 4;                          // 0.4 MB
    int* bucket = (int*)(ws + off); off += (size_t)n * CAP * 4;                    // 25.6 MB

    hipMemsetAsync(deg, 0, (size_t)n * 4, stream);

    int PB = (n + 63) / 64;              // 1563 proj blocks
    int BB = (E + 255) / 256;            // 5000 build blocks
    prep_kernel<<<PB + BB, 256, 0, stream>>>(x, qk_w, qk_b, v_w, v_b,
                                             eidx, deg, qkv, bucket, n, E, PB);
    attn_kernel<<<(n + 3) / 4, 256, 0, stream>>>(x, qkv, deg, bucket,
                                                 o_w, o_b, ln_g, ln_b,
                                                 (float*)d_out, n);
}

// Round 9
// 207.863 us; speedup vs baseline: 1.3678x; 1.1105x over previous
//
#include <hip/hip_runtime.h>
#include <hip/hip_bf16.h>
#include <math.h>

#define DD 64
#define CAP 64
#define LN_EPS 1e-5f

__device__ __forceinline__ float bf2f(unsigned short u) {
    return __uint_as_float(((unsigned)u) << 16);
}
__device__ __forceinline__ float rlane(float v, int l) {
    return __int_as_float(__builtin_amdgcn_readlane(__float_as_int(v), l));
}

// ---------------- Kernel 1 (fused): blocks [0,PB) = projections -> interleaved
// bf16 QKV rows (256B/node); blocks [PB,..) = XCD-SLICED bucket build:
// build block local=bid-PB runs on XCD (bid%8)==(local%8) [PB%8==0]; group g
// scans ALL edge dst's (coalesced, cache-resident) but only places edges whose
// dst lies in its contiguous node-slice [g*sd,(g+1)*sd) -> bucket writes are
// confined to a 3.2MB region that FITS the local 4MB L2 (kills the per-store
// evict-writeback measured in r8: WRITE_SIZE 102MB, ~64B/scattered store).
__global__ __launch_bounds__(256) void prep_kernel(
    const float* __restrict__ x,
    const float* __restrict__ qk_w, const float* __restrict__ qk_b,
    const float* __restrict__ v_w,  const float* __restrict__ v_b,
    const int* __restrict__ eidx, int* __restrict__ deg,
    __hip_bfloat16* __restrict__ qkv, int* __restrict__ bucket,
    int n, int E, int PB, int sd)
{
    int bid = blockIdx.x;
    if (bid < PB) {
        int tid = threadIdx.x;
        int wave = tid >> 6, lane = tid & 63;
        const float* W = (wave & 2) ? v_w : qk_w;
        const float* B = (wave & 2) ? v_b : qk_b;
        int half = (wave & 2) ? 64 : 0;
        float w[64];
        #pragma unroll
        for (int j = 0; j < 64; ++j) w[j] = W[lane * 64 + j];
        float bias = B[lane];
        int base = bid * 64 + (wave & 1) * 32;
        for (int k = 0; k < 32; k += 2) {
            int n0 = base + k, n1 = n0 + 1;
            if (n0 >= n) break;                      // uniform per wave
            float xv0 = x[(size_t)n0 * 64 + lane];
            float xv1 = (n1 < n) ? x[(size_t)n1 * 64 + lane] : 0.f;
            float a0 = bias, a1 = bias;
            #pragma unroll
            for (int j = 0; j < 64; ++j) {
                a0 = fmaf(rlane(xv0, j), w[j], a0);
                a1 = fmaf(rlane(xv1, j), w[j], a1);
            }
            qkv[(size_t)n0 * 128 + half + lane] = __float2bfloat16(a0);
            if (n1 < n) qkv[(size_t)n1 * 128 + half + lane] = __float2bfloat16(a1);
        }
    } else {
        int local = bid - PB;
        int g     = local & 7;                       // == bid%8 == XCD (perf hint)
        int chunk = local >> 3;
        int lo = g * sd;
        const int* dst = eidx + E;
        int base = chunk * 2048 + threadIdx.x;
        #pragma unroll
        for (int k = 0; k < 8; ++k) {
            int i = base + k * 256;
            if (i < E) {
                int d = dst[i];                      // coalesced, L2/L3-resident
                unsigned rel = (unsigned)(d - lo);
                if (rel < (unsigned)sd) {            // in my slice
                    int s = eidx[i];
                    int r = atomicAdd(&deg[d], 1);
                    if (r < CAP) bucket[(d << 6) + r] = s;
                }
            }
        }
    }
}

// ---------------- Kernel 2: per-node attention + o-proj + residual + LayerNorm
// 4 waves/block = 4 nodes. Wave = 4x16-lane subgroups (lane holds 4 dims,
// bf16x4 = 8B), 2-deep unroll -> 8 edges in flight, clean main loop + tail.
// Interleaved QKV: one 32-bit byte offset per edge, v half at +128 immediate.
// Fixed softmax shift m=5 (scores clamped to [-5,5]).
__global__ __launch_bounds__(256) void attn_kernel(
    const float* __restrict__ x, const __hip_bfloat16* __restrict__ qkv,
    const int* __restrict__ deg, const int* __restrict__ bucket,
    const float* __restrict__ o_w, const float* __restrict__ o_b,
    const float* __restrict__ ln_g, const float* __restrict__ ln_b,
    float* __restrict__ out, int n)
{
    __shared__ float low[64 * 68];                 // o_w, stride 68 (16B-aligned)
    int tid = threadIdx.x;
    for (int i = tid; i < 64 * 64; i += 256)
        low[(i >> 6) * 68 + (i & 63)] = o_w[i];
    __syncthreads();

    int wave = tid >> 6, lane = tid & 63;
    int node = blockIdx.x * 4 + wave;
    if (node >= n) return;

    int sub = lane >> 4;                           // edge slot 0..3
    int sl  = lane & 15;                           // dims sl*4 .. sl*4+3

    const char* base = (const char*)qkv;
    ushort4 qu = *(const ushort4*)(base + (size_t)node * 256 + sl * 8);
    float4 q4 = make_float4(bf2f(qu.x), bf2f(qu.y), bf2f(qu.z), bf2f(qu.w));
    int dn = deg[node]; if (dn > CAP) dn = CAP;
    const int* bkt = bucket + (node << 6);

    float s = 0.f;
    float4 acc = {0.f, 0.f, 0.f, 0.f};

    int idx = sub;
    for (; idx + 4 < dn; idx += 8) {               // 2 edges/subgroup iter
        int s0 = bkt[idx];
        int s1 = bkt[idx + 4];
        unsigned o0 = ((unsigned)s0 << 8) + (sl << 3);
        unsigned o1 = ((unsigned)s1 << 8) + (sl << 3);
        ushort4 k0 = *(const ushort4*)(base + o0);
        ushort4 k1 = *(const ushort4*)(base + o1);
        ushort4 u0 = *(const ushort4*)(base + o0 + 128);
        ushort4 u1 = *(const ushort4*)(base + o1 + 128);
        float p0 = q4.x*bf2f(k0.x) + q4.y*bf2f(k0.y) + q4.z*bf2f(k0.z) + q4.w*bf2f(k0.w);
        float p1 = q4.x*bf2f(k1.x) + q4.y*bf2f(k1.y) + q4.z*bf2f(k1.z) + q4.w*bf2f(k1.w);
        #pragma unroll
        for (int w = 1; w <= 8; w <<= 1) { p0 += __shfl_xor(p0, w); p1 += __shfl_xor(p1, w); }
        float sc0 = fminf(5.f, fmaxf(-5.f, p0 * 0.125f));
        float sc1 = fminf(5.f, fmaxf(-5.f, p1 * 0.125f));
        float pe0 = __expf(sc0 - 5.f);
        float pe1 = __expf(sc1 - 5.f);
        s += pe0 + pe1;
        acc.x += pe0 * bf2f(u0.x) + pe1 * bf2f(u1.x);
        acc.y += pe0 * bf2f(u0.y) + pe1 * bf2f(u1.y);
        acc.z += pe0 * bf2f(u0.z) + pe1 * bf2f(u1.z);
        acc.w += pe0 * bf2f(u0.w) + pe1 * bf2f(u1.w);
    }
    if (idx < dn) {
        int s0 = bkt[idx];
        unsigned o0 = ((unsigned)s0 << 8) + (sl << 3);
        ushort4 k0 = *(const ushort4*)(base + o0);
        ushort4 u0 = *(const ushort4*)(base + o0 + 128);
        float p0 = q4.x*bf2f(k0.x) + q4.y*bf2f(k0.y) + q4.z*bf2f(k0.z) + q4.w*bf2f(k0.w);
        #pragma unroll
        for (int w = 1; w <= 8; w <<= 1) p0 += __shfl_xor(p0, w);
        float sc0 = fminf(5.f, fmaxf(-5.f, p0 * 0.125f));
        float pe0 = __expf(sc0 - 5.f);
        s += pe0;
        acc.x += pe0 * bf2f(u0.x); acc.y += pe0 * bf2f(u0.y);
        acc.z += pe0 * bf2f(u0.z); acc.w += pe0 * bf2f(u0.w);
    }

    // merge 4 subgroup partials (plain sums, fixed shift) — butterfly:
    // afterwards every lane holds totals for its sl's 4 dims.
    s += __shfl_xor(s, 16); s += __shfl_xor(s, 32);
    acc.x += __shfl_xor(acc.x, 16); acc.x += __shfl_xor(acc.x, 32);
    acc.y += __shfl_xor(acc.y, 16); acc.y += __shfl_xor(acc.y, 32);
    acc.z += __shfl_xor(acc.z, 16); acc.z += __shfl_xor(acc.z, 32);
    acc.w += __shfl_xor(acc.w, 16); acc.w += __shfl_xor(acc.w, 32);

    float inv = (dn > 0) ? (1.0f / s) : 0.f;       // s>0 iff deg>0 (pe >= e^-10)
    acc.x *= inv; acc.y *= inv; acc.z *= inv; acc.w *= inv;

    // o-projection: outd[4i+c] lives in lane i comp c -> readlane broadcast;
    // weights via ds_read_b128 (stride-68, 16B-aligned, conflict-free).
    float y = o_b[lane];
    const float4* lw = (const float4*)(low + lane * 68);
    #pragma unroll
    for (int i = 0; i < 16; ++i) {
        float4 wv = lw[i];
        y = fmaf(rlane(acc.x, i), wv.x, y);
        y = fmaf(rlane(acc.y, i), wv.y, y);
        y = fmaf(rlane(acc.z, i), wv.z, y);
        y = fmaf(rlane(acc.w, i), wv.w, y);
    }

    float h = y + x[(size_t)node * 64 + lane];
    float mean = h;
    #pragma unroll
    for (int w = 1; w <= 32; w <<= 1) mean += __shfl_xor(mean, w);
    mean *= (1.f / 64.f);
    float d0 = h - mean;
    float dv = d0 * d0;
    #pragma unroll
    for (int w = 1; w <= 32; w <<= 1) dv += __shfl_xor(dv, w);
    dv *= (1.f / 64.f);
    float r = rsqrtf(dv + LN_EPS);
    out[(size_t)node * 64 + lane] = d0 * r * ln_g[lane] + ln_b[lane];
}

extern "C" void kernel_launch(void* const* d_in, const int* in_sizes, int n_in,
                              void* d_out, int out_size, void* d_ws, size_t ws_size,
                              hipStream_t stream)
{
    const float* x    = (const float*)d_in[0];
    const int*   eidx = (const int*)  d_in[1];
    const float* qk_w = (const float*)d_in[2];
    const float* qk_b = (const float*)d_in[3];
    const float* v_w  = (const float*)d_in[4];
    const float* v_b  = (const float*)d_in[5];
    const float* o_w  = (const float*)d_in[6];
    const float* o_b  = (const float*)d_in[7];
    const float* ln_g = (const float*)d_in[8];
    const float* ln_b = (const float*)d_in[9];

    const int n = in_sizes[0] / DD;      // 100000
    const int E = in_sizes[1] / 2;       // 1280000

    char* ws = (char*)d_ws;
    size_t off = 0;
    __hip_bfloat16* qkv = (__hip_bfloat16*)(ws + off); off += (size_t)n * 128 * 2; // 25.6 MB
    int* deg    = (int*)(ws + off); off += (size_t)n * 4;                          // 0.4 MB
    int* bucket = (int*)(ws + off); off += (size_t)n * CAP * 4;                    // 25.6 MB

    hipMemsetAsync(deg, 0, (size_t)n * 4, stream);

    int PB = ((n + 63) / 64 + 7) & ~7;   // 1568 proj blocks (mult of 8 -> build
                                         // block XCD phase == local%8)
    int NCH = (E + 2047) / 2048;         // 625 chunks of 2048 edges
    int BB  = NCH * 8;                   // 5000 build blocks (8 slice groups)
    int sd  = (n + 7) / 8;               // 12500 nodes per slice
    prep_kernel<<<PB + BB, 256, 0, stream>>>(x, qk_w, qk_b, v_w, v_b,
                                             eidx, deg, qkv, bucket, n, E, PB, sd);
    attn_kernel<<<(n + 3) / 4, 256, 0, stream>>>(x, qkv, deg, bucket,
                                                 o_w, o_b, ln_g, ln_b,
                                                 (float*)d_out, n);
}